// Round 3
// baseline (7742.023 us; speedup 1.0000x reference)
//
#include <hip/hip_runtime.h>
#include <hip/hip_bf16.h>

// B=64, S=512, T=64, E=H=512, V=128, G=4H=2048, Kgates=1152
// One persistent kernel (512 blocks, 2/CU) runs all 64 steps, 2 grid barriers
// per step. Gates GEMM fused with split-K reduce + LSTM cell via per-chunk
// arrival counters. All per-step GEMM operands pre-transposed for conflict-
// free coalesced staging. c-state lives in registers; h double-buffered.

#define DI __device__ __forceinline__
typedef __hip_bfloat16 bf16;
typedef __hip_bfloat162 bf162;

DI float2 bf2f2(unsigned int u) {
  bf162 b = *reinterpret_cast<const bf162*>(&u);
  return __bfloat1622float2(b);
}
DI float sigm(float x) { return 1.f / (1.f + expf(-x)); }

// ---------------------------------------------------------------------------
// Generic 64x64-tile fp32 GEMM (precompute only).
// BT: B is (N x K) row-major. OBF: bf16 out. CT: transpose within 512-row
// batch block -> C[b][n][s].
// ---------------------------------------------------------------------------
template<bool BT, bool OBF, bool CT>
__launch_bounds__(256)
__global__ void gemm64(const float* __restrict__ A, const float* __restrict__ Bm,
                       void* __restrict__ Cp, const float* __restrict__ bias,
                       int M, int N, int K, int lda, int ldb, int ldc) {
  __shared__ __align__(16) float As[16][68];
  __shared__ __align__(16) float Bs[16][68];
  const int tid = threadIdx.x;
  const int n0 = blockIdx.x * 64;
  const int m0 = blockIdx.y * 64;
  const int tx = tid & 15, ty = tid >> 4;
  const int arow = tid >> 2;
  const int acol = (tid & 3) * 4;
  float acc[4][4] = {};
  for (int k0 = 0; k0 < K; k0 += 16) {
    float4 a4 = *(const float4*)&A[(size_t)(m0 + arow) * lda + k0 + acol];
    As[acol + 0][arow] = a4.x; As[acol + 1][arow] = a4.y;
    As[acol + 2][arow] = a4.z; As[acol + 3][arow] = a4.w;
    if (BT) {
      float4 b4 = *(const float4*)&Bm[(size_t)(n0 + arow) * ldb + k0 + acol];
      Bs[acol + 0][arow] = b4.x; Bs[acol + 1][arow] = b4.y;
      Bs[acol + 2][arow] = b4.z; Bs[acol + 3][arow] = b4.w;
    } else {
      const int brow = tid >> 4;
      const int bcol = (tid & 15) * 4;
      float4 b4 = *(const float4*)&Bm[(size_t)(k0 + brow) * ldb + n0 + bcol];
      *(float4*)&Bs[brow][bcol] = b4;
    }
    __syncthreads();
#pragma unroll
    for (int kk = 0; kk < 16; kk++) {
      float4 av = *(const float4*)&As[kk][ty * 4];
      float4 bv = *(const float4*)&Bs[kk][tx * 4];
      float a_[4] = {av.x, av.y, av.z, av.w};
      float b_[4] = {bv.x, bv.y, bv.z, bv.w};
#pragma unroll
      for (int i = 0; i < 4; i++)
#pragma unroll
        for (int j = 0; j < 4; j++) acc[i][j] += a_[i] * b_[j];
    }
    __syncthreads();
  }
#pragma unroll
  for (int i = 0; i < 4; i++) {
    const int m = m0 + ty * 4 + i;
#pragma unroll
    for (int j = 0; j < 4; j++) {
      const int n = n0 + tx * 4 + j;
      float v = acc[i][j] + (bias ? bias[n] : 0.f);
      if (OBF) {
        if (CT) {
          int bb = m >> 9, sE = m & 511;
          ((bf16*)Cp)[((size_t)bb << 18) + (size_t)n * 512 + sE] = __float2bfloat16(v);
        } else {
          ((bf16*)Cp)[(size_t)m * ldc + n] = __float2bfloat16(v);
        }
      } else {
        ((float*)Cp)[(size_t)m * ldc + n] = v;
      }
    }
  }
}

// ---------------------------------------------------------------------------
// Small precompute kernels
// ---------------------------------------------------------------------------
__launch_bounds__(256)
__global__ void transpose512(const float* __restrict__ src, float* __restrict__ dst) {
  int idx = blockIdx.x * 256 + threadIdx.x;
  int r = idx >> 9, c = idx & 511;
  dst[(size_t)c * 512 + r] = src[idx];
}

__launch_bounds__(256)
__global__ void colvec_kernel(const float* __restrict__ bvec, const float* __restrict__ W,
                              float* __restrict__ outv) {
  int e = blockIdx.x * 256 + threadIdx.x;
  float acc = 0.f;
  for (int f = 0; f < 512; f++) acc += bvec[f] * W[(size_t)f * 512 + e];
  outv[e] = acc;
}

__launch_bounds__(256)
__global__ void dot_kernel(const float* __restrict__ a, const float* __restrict__ b,
                           float* __restrict__ outp) {
  __shared__ float red[256];
  int tid = threadIdx.x;
  red[tid] = a[tid] * b[tid] + a[tid + 256] * b[tid + 256];
  __syncthreads();
  for (int st = 128; st > 0; st >>= 1) {
    if (tid < st) red[tid] += red[tid + st];
    __syncthreads();
  }
  if (tid == 0) *outp = red[0];
}

__launch_bounds__(256)
__global__ void svec_kernel(const float* __restrict__ mem, const float* __restrict__ wb,
                            const float* __restrict__ dotc, float* __restrict__ svec) {
  __shared__ __align__(16) float ws_[512];
  int tid = threadIdx.x;
  *(float2*)&ws_[tid * 2] = *(const float2*)&wb[tid * 2];
  __syncthreads();
  int bs = blockIdx.x * 256 + tid;
  const float4* mr = (const float4*)&mem[(size_t)bs * 512];
  const float4* w4 = (const float4*)ws_;
  float acc = *dotc;
#pragma unroll 4
  for (int j = 0; j < 128; j++) {
    float4 m = mr[j], w = w4[j];
    acc += m.x * w.x + m.y * w.y + m.z * w.z + m.w * w.w;
  }
  svec[bs] = acc;
}

__launch_bounds__(256)
__global__ void biasg_kernel(const float* __restrict__ W_ih, const float* __restrict__ b_ih,
                             const float* __restrict__ b_hh, const float* __restrict__ bo,
                             float* __restrict__ biasg) {
  int j = blockIdx.x * 256 + threadIdx.x;
  float acc = b_ih[j] + b_hh[j];
  const float4* wr = (const float4*)&W_ih[(size_t)j * 640];
  const float4* br = (const float4*)bo;
#pragma unroll 4
  for (int f4 = 0; f4 < 128; f4++) {
    float4 w = wr[f4], bb = br[f4];
    acc += w.x * bb.x + w.y * bb.y + w.z * bb.z + w.w * bb.w;
  }
  biasg[j] = acc;
}

__launch_bounds__(256)
__global__ void wcomb_copy(const float* __restrict__ W_hh, const float* __restrict__ W_ih,
                           float* __restrict__ Wcomb) {
  int idx = blockIdx.x * 256 + threadIdx.x;
  int j = idx / 640, cc = idx % 640;
  float v = (cc < 512) ? W_hh[(size_t)j * 512 + cc] : W_ih[(size_t)j * 640 + cc];
  Wcomb[(size_t)j * 1152 + 512 + cc] = v;
}

// WcombT[k][j'=d*4+g] = Wcomb[g*512+d][k]   (gate-interleaved, k-major)
__launch_bounds__(256)
__global__ void reorderW(const float* __restrict__ Wc, float* __restrict__ WcT) {
  int jp = blockIdx.x * 256 + threadIdx.x;   // 0..2047
  int k  = blockIdx.y;                       // 0..1151
  WcT[(size_t)k * 2048 + jp] = Wc[((size_t)(jp & 3) * 512 + (jp >> 2)) * 1152 + k];
}

__launch_bounds__(256)
__global__ void reorderB(const float* __restrict__ bg, float* __restrict__ bg2) {
  int jp = blockIdx.x * 256 + threadIdx.x;   // 0..2047
  bg2[jp] = bg[(size_t)(jp & 3) * 512 + (jp >> 2)];
}

// tgtT[t][v][b] = tgt[b][t][v]
__launch_bounds__(256)
__global__ void transposeT(const float* __restrict__ tg, float* __restrict__ tgT) {
  int idx = blockIdx.x * 256 + threadIdx.x;  // < 524288
  int b = idx & 63, tv = idx >> 6;
  int t = tv >> 7, v = tv & 127;
  tgT[idx] = tg[((size_t)b * 64 + t) * 128 + v];
}

// ---------------------------------------------------------------------------
// Persistent step-loop: 512 blocks x 256 threads, 2 grid barriers / step.
// ---------------------------------------------------------------------------
struct SMemA { float hs[512]; float buf[2112]; float p[64]; float red[4]; };
struct SMemB { __align__(16) float As[144][68]; __align__(16) float Bs[144][36]; };
union SMemU { SMemA a; SMemB b; };   // 59904 B -> 2 blocks/CU

DI void gbar(unsigned* flags, unsigned* gosig, int slot) {
  const unsigned tgt = (unsigned)slot + 1u;
  __syncthreads();
  if (threadIdx.x == 0) {
    __threadfence();
    __hip_atomic_store(&flags[blockIdx.x], tgt, __ATOMIC_RELAXED, __HIP_MEMORY_SCOPE_AGENT);
  }
  if (blockIdx.x == 0) {
    while (__hip_atomic_load(&flags[threadIdx.x], __ATOMIC_RELAXED, __HIP_MEMORY_SCOPE_AGENT) < tgt ||
           __hip_atomic_load(&flags[threadIdx.x + 256], __ATOMIC_RELAXED, __HIP_MEMORY_SCOPE_AGENT) < tgt)
      __builtin_amdgcn_s_sleep(2);
    __syncthreads();
    if (threadIdx.x == 0) {
      __threadfence();
      __hip_atomic_store(gosig, tgt, __ATOMIC_RELAXED, __HIP_MEMORY_SCOPE_AGENT);
    }
  }
  if (threadIdx.x == 0) {
    while (__hip_atomic_load(gosig, __ATOMIC_RELAXED, __HIP_MEMORY_SCOPE_AGENT) < tgt)
      __builtin_amdgcn_s_sleep(2);
    __threadfence();
  }
  __syncthreads();
}

__launch_bounds__(256, 2)
__global__ void step_loop(const bf16* __restrict__ K2T, const bf16* __restrict__ Vv,
                          const float* __restrict__ svec, const float* __restrict__ WcombT,
                          const float* __restrict__ biasg2, const float* __restrict__ tgtT,
                          const float* __restrict__ Wcls, const float* __restrict__ bcls,
                          float* __restrict__ hA, float* __restrict__ hB,
                          float* __restrict__ hTA, float* __restrict__ hTB,
                          float* __restrict__ ctxT, float* __restrict__ mlval,
                          unsigned* mlcnt, unsigned* gcnt, unsigned* flags, unsigned* gosig,
                          float* __restrict__ gpart, float* __restrict__ out) {
  __shared__ SMemU sm;
  const int blk = blockIdx.x, tid = threadIdx.x;
  const int b = blk >> 3, jj = blk & 7, s0 = jj * 64;   // phase A role
  const int ks = blk >> 6, nc = blk & 63;               // phase B role
  const float SCALE = 0.04419417382415922f;             // 1/sqrt(512)
  float cval = 0.f;                                     // register-resident c state
  int slot = 0;

  for (int t = 0; t <= 64; t++) {
    const float* hR  = (t & 1) ? hB : hA;    // h for this step
    const float* hTR = (t & 1) ? hTB : hTA;
    float* hW  = (t & 1) ? hA : hB;          // h for next step
    float* hTW = (t & 1) ? hTA : hTB;

    // ---- load h into LDS ----
    *(float2*)&sm.a.hs[2 * tid] = *(const float2*)&hR[(size_t)b * 512 + 2 * tid];
    __syncthreads();

    // ---- classifier: out[t-1] (16 v's per block) ----
    if (t > 0) {
      const int v = jj * 16 + (tid >> 4), part = tid & 15;
      const float4* wr = (const float4*)&Wcls[(size_t)v * 512 + part * 32];
      const float4* hr = (const float4*)&sm.a.hs[part * 32];
      float a = 0.f;
#pragma unroll
      for (int q = 0; q < 8; q++) {
        float4 w = wr[q], x = hr[q];
        a += w.x * x.x + w.y * x.y + w.z * x.z + w.w * x.w;
      }
      a += __shfl_xor(a, 1); a += __shfl_xor(a, 2);
      a += __shfl_xor(a, 4); a += __shfl_xor(a, 8);
      if (part == 0) out[((size_t)b * 64 + (t - 1)) * 128 + v] = a + bcls[v];
    }
    if (t == 64) return;

    // ================= PHASE A: attention (8 blocks per b) =================
    if (tid < 64)
      __hip_atomic_store(&ctxT[(size_t)(jj * 64 + tid) * 64 + b], 0.f,
                         __ATOMIC_RELAXED, __HIP_MEMORY_SCOPE_AGENT);
    // scores partials: eg = tid>>3 covers 16 e's, sg = tid&7 covers 8 s's
    {
      const int eg = tid >> 3, sg = tid & 7;
      float a8[8] = {};
      const uint4* kp = (const uint4*)&K2T[((size_t)b << 18) + (size_t)(eg * 16) * 512 + s0 + 8 * sg];
#pragma unroll 4
      for (int i = 0; i < 16; i++) {
        uint4 q = kp[(size_t)i * 64];
        float he = sm.a.hs[eg * 16 + i];
        float2 p0 = bf2f2(q.x), p1 = bf2f2(q.y), p2 = bf2f2(q.z), p3 = bf2f2(q.w);
        a8[0] += he * p0.x; a8[1] += he * p0.y; a8[2] += he * p1.x; a8[3] += he * p1.y;
        a8[4] += he * p2.x; a8[5] += he * p2.y; a8[6] += he * p3.x; a8[7] += he * p3.y;
      }
#pragma unroll
      for (int y = 0; y < 8; y++) sm.a.buf[eg * 66 + sg * 8 + y] = a8[y];
    }
    __syncthreads();   // S1
    if (tid < 64) {
      float sv = 0.f;
#pragma unroll
      for (int eg = 0; eg < 32; eg++) sv += sm.a.buf[eg * 66 + tid];
      float pvl = (sv + svec[(size_t)b * 512 + s0 + tid]) * SCALE;
      float mv = pvl;
#pragma unroll
      for (int off = 32; off; off >>= 1) mv = fmaxf(mv, __shfl_xor(mv, off));
      float evl = __expf(pvl - mv);
      sm.a.p[tid] = evl;
      float lv = evl;
#pragma unroll
      for (int off = 32; off; off >>= 1) lv += __shfl_xor(lv, off);
      if (tid == 0) { sm.a.red[0] = mv; sm.a.red[1] = lv; }
    }
    __syncthreads();   // S2 (p, red visible; buf reads done)
    if (tid == 0) {
      __hip_atomic_store(&mlval[((size_t)b * 8 + jj) * 2 + 0], sm.a.red[0],
                         __ATOMIC_RELAXED, __HIP_MEMORY_SCOPE_AGENT);
      __hip_atomic_store(&mlval[((size_t)b * 8 + jj) * 2 + 1], sm.a.red[1],
                         __ATOMIC_RELAXED, __HIP_MEMORY_SCOPE_AGENT);
      __builtin_amdgcn_fence(__ATOMIC_RELEASE, "agent");
      __hip_atomic_fetch_add(&mlcnt[b], 1u, __ATOMIC_RELAXED, __HIP_MEMORY_SCOPE_AGENT);
    }
    // ctx partials: wave w covers 16 s's, lane l covers e = 8l..8l+7
    {
      const int w = tid >> 6, l = tid & 63;
      float c8[8] = {};
      const uint4* vp = (const uint4*)&Vv[((size_t)b << 18) + (size_t)(s0 + w * 16) * 512 + 8 * l];
#pragma unroll 4
      for (int i = 0; i < 16; i++) {
        float ps = sm.a.p[w * 16 + i];
        uint4 q = vp[(size_t)i * 64];
        float2 p0 = bf2f2(q.x), p1 = bf2f2(q.y), p2 = bf2f2(q.z), p3 = bf2f2(q.w);
        c8[0] += ps * p0.x; c8[1] += ps * p0.y; c8[2] += ps * p1.x; c8[3] += ps * p1.y;
        c8[4] += ps * p2.x; c8[5] += ps * p2.y; c8[6] += ps * p3.x; c8[7] += ps * p3.y;
      }
      *(float4*)&sm.a.buf[w * 520 + 8 * l]     = make_float4(c8[0], c8[1], c8[2], c8[3]);
      *(float4*)&sm.a.buf[w * 520 + 8 * l + 4] = make_float4(c8[4], c8[5], c8[6], c8[7]);
    }
    __syncthreads();   // S3
    if (tid == 0) {
      while (__hip_atomic_load(&mlcnt[b], __ATOMIC_RELAXED, __HIP_MEMORY_SCOPE_AGENT) < 8u * (t + 1))
        __builtin_amdgcn_s_sleep(1);
      float mj[8], lj[8], M = -1e30f;
#pragma unroll
      for (int q = 0; q < 8; q++) {
        mj[q] = __hip_atomic_load(&mlval[((size_t)b * 8 + q) * 2 + 0], __ATOMIC_RELAXED, __HIP_MEMORY_SCOPE_AGENT);
        lj[q] = __hip_atomic_load(&mlval[((size_t)b * 8 + q) * 2 + 1], __ATOMIC_RELAXED, __HIP_MEMORY_SCOPE_AGENT);
        M = fmaxf(M, mj[q]);
      }
      float L = 0.f;
#pragma unroll
      for (int q = 0; q < 8; q++) L += __expf(mj[q] - M) * lj[q];
      sm.a.red[2] = __expf(mj[jj] - M) / L;
    }
    __syncthreads();   // S4
    {
      const float msc = sm.a.red[2];
      float cx = sm.a.buf[tid] + sm.a.buf[520 + tid] + sm.a.buf[1040 + tid] + sm.a.buf[1560 + tid];
      float cy = sm.a.buf[tid + 256] + sm.a.buf[520 + tid + 256] +
                 sm.a.buf[1040 + tid + 256] + sm.a.buf[1560 + tid + 256];
      atomicAdd(&ctxT[(size_t)tid * 64 + b], cx * msc);
      atomicAdd(&ctxT[(size_t)(tid + 256) * 64 + b], cy * msc);
    }
    gbar(flags, gosig, slot++);

    // ====== PHASE B+C: gates GEMM (8 ks x 64 nc) + fused reduce + cell ======
    {
      const int k0 = ks * 144;
      for (int q = tid; q < 2304; q += 256) {
        const int row = q >> 4, c4 = (q & 15) * 4;
        const int k = k0 + row;
        float4 xv;
        if (k < 512)       xv = *(const float4*)&ctxT[(size_t)k * 64 + c4];
        else if (k < 1024) xv = *(const float4*)&hTR[(size_t)(k - 512) * 64 + c4];
        else               xv = *(const float4*)&tgtT[((size_t)t * 128 + (k - 1024)) * 64 + c4];
        *(float4*)&sm.b.As[row][c4] = xv;
      }
      for (int q = tid; q < 1152; q += 256) {
        const int row = q >> 3, c4 = (q & 7) * 4;
        *(float4*)&sm.b.Bs[row][c4] = *(const float4*)&WcombT[(size_t)(k0 + row) * 2048 + nc * 32 + c4];
      }
      __syncthreads();
      const int tx = tid & 7, ty = tid >> 3;   // ty: 2 b-rows, tx: 4 cols
      float acc[2][4] = {};
#pragma unroll 4
      for (int kk = 0; kk < 144; kk++) {
        float2 av = *(const float2*)&sm.b.As[kk][ty * 2];
        float4 bv = *(const float4*)&sm.b.Bs[kk][tx * 4];
        acc[0][0] += av.x * bv.x; acc[0][1] += av.x * bv.y;
        acc[0][2] += av.x * bv.z; acc[0][3] += av.x * bv.w;
        acc[1][0] += av.y * bv.x; acc[1][1] += av.y * bv.y;
        acc[1][2] += av.y * bv.z; acc[1][3] += av.y * bv.w;
      }
#pragma unroll
      for (int i = 0; i < 2; i++)
        *(float4*)&gpart[((size_t)ks * 64 + ty * 2 + i) * 2048 + nc * 32 + tx * 4] =
            make_float4(acc[i][0], acc[i][1], acc[i][2], acc[i][3]);
    }
    __syncthreads();
    if (tid == 0) {
      __builtin_amdgcn_fence(__ATOMIC_RELEASE, "agent");
      __hip_atomic_fetch_add(&gcnt[nc], 1u, __ATOMIC_RELAXED, __HIP_MEMORY_SCOPE_AGENT);
      while (__hip_atomic_load(&gcnt[nc], __ATOMIC_RELAXED, __HIP_MEMORY_SCOPE_AGENT) < 8u * (t + 1))
        __builtin_amdgcn_s_sleep(1);
      __builtin_amdgcn_fence(__ATOMIC_ACQUIRE, "agent");
    }
    __syncthreads();
    {
      // reduce slice: b in [ks*8, ks*8+8), cols nc*32..nc*32+31
      const int bb = ks * 8 + (tid >> 5);
      const int col = tid & 31;
      const int d = nc * 8 + ((tid >> 2) & 7);
      float val = biasg2[nc * 32 + col];
#pragma unroll
      for (int k2 = 0; k2 < 8; k2++)
        val += gpart[((size_t)k2 * 64 + bb) * 2048 + nc * 32 + col];
      const int qbase = (tid & 63) & ~3;
      float gi = __shfl(val, qbase + 0);
      float gf = __shfl(val, qbase + 1);
      float gg = __shfl(val, qbase + 2);
      float go_ = __shfl(val, qbase + 3);
      float cn = sigm(gf) * cval + sigm(gi) * tanhf(gg);
      cval = cn;
      float hn = sigm(go_) * tanhf(cn);
      const int g = tid & 3;
      if (g == 0)      hW[(size_t)bb * 512 + d] = hn;
      else if (g == 1) hTW[(size_t)d * 64 + bb] = hn;
    }
    gbar(flags, gosig, slot++);
  }
}

// ---------------------------------------------------------------------------
extern "C" void kernel_launch(void* const* d_in, const int* in_sizes, int n_in,
                              void* d_out, int out_size, void* d_ws, size_t ws_size,
                              hipStream_t stream) {
  const float* memory = (const float*)d_in[0];
  const float* tgt    = (const float*)d_in[1];
  const float* Wq     = (const float*)d_in[2];
  const float* bq     = (const float*)d_in[3];
  const float* Wk     = (const float*)d_in[4];
  const float* bk     = (const float*)d_in[5];
  const float* Wv     = (const float*)d_in[6];
  const float* bv     = (const float*)d_in[7];
  const float* Wo     = (const float*)d_in[8];
  const float* bo     = (const float*)d_in[9];
  const float* W_ih   = (const float*)d_in[10];
  const float* b_ih   = (const float*)d_in[11];
  const float* W_hh   = (const float*)d_in[12];
  const float* b_hh   = (const float*)d_in[13];
  const float* Wcls   = (const float*)d_in[14];
  const float* bcls   = (const float*)d_in[15];
  float* out = (float*)d_out;

  float* ws = (float*)d_ws;
  size_t off = 0;
  auto alloc = [&](size_t n) { size_t r = off; off += (n + 15) & ~(size_t)15; return r; };
  const size_t K2_off     = alloc(8388608);   // bf16 x16.7M: K2T [b][e][s]
  const size_t V_off      = alloc(8388608);   // bf16 x16.7M: V   [b][s][e]
  const size_t WcombT_off = alloc(2359296);   // fp32 [k][j'] 1152x2048
  const size_t svec_off   = alloc(32768);
  const size_t sb_off     = alloc(512);
  const size_t wb_off     = alloc(512);
  const size_t dotc_off   = alloc(16);
  const size_t biasg_off  = alloc(2048);
  const size_t biasg2_off = alloc(2048);
  const size_t tgtT_off   = alloc(524288);    // [t][v][b]
  const size_t zero_off   = alloc(67584);     // h0(32768) hT0(32768) sync(2048)
  const size_t h1_off     = alloc(32768);
  const size_t hT1_off    = alloc(32768);
  const size_t ctxT_off   = alloc(32768);     // [e][b]
  const size_t mlval_off  = alloc(1024);
  const size_t scr_off    = alloc(2883584);   // precompute: Wcomb+Wkq+WkT / loop: gpart

  bf16* K2T = (bf16*)(ws + K2_off);
  bf16* Vv  = (bf16*)(ws + V_off);
  float* h0   = ws + zero_off;
  float* hT0  = h0 + 32768;
  unsigned* sync = (unsigned*)(hT0 + 32768);
  unsigned* flags = sync;            // 512
  unsigned* gosig = sync + 512;      // 1
  unsigned* mlcnt = sync + 576;      // 64
  unsigned* gcnt  = sync + 640;      // 64
  float* Wcomb = ws + scr_off;                // precompute phase
  float* Wkq   = Wcomb + 2359296;
  float* WkT   = Wkq + 262144;
  float* gpart = ws + scr_off;                // loop phase (overlaps Wcomb)

  // zero h0, hT0, sync counters
  hipMemsetAsync(h0, 0, 67584 * sizeof(float), stream);

  // ---- precompute (step-invariant) ----
  transpose512<<<1024, 256, 0, stream>>>(Wk, WkT);
  colvec_kernel<<<2, 256, 0, stream>>>(bk, Wq, ws + sb_off);   // sb[e]=sum_f bk[f]Wq[f,e]
  colvec_kernel<<<2, 256, 0, stream>>>(bq, Wk, ws + wb_off);   // wb[m]=sum_f bq[f]Wk[f,m]
  dot_kernel<<<1, 256, 0, stream>>>(bq, bk, ws + dotc_off);
  gemm64<false, false, false><<<dim3(8, 8), 256, 0, stream>>>(
      WkT, Wq, Wkq, nullptr, 512, 512, 512, 512, 512, 512);
  gemm64<false, true, true><<<dim3(8, 512), 256, 0, stream>>>(
      memory, Wkq, K2T, ws + sb_off, 32768, 512, 512, 512, 512, 512);
  gemm64<true, true, false><<<dim3(8, 512), 256, 0, stream>>>(
      memory, Wv, Vv, bv, 32768, 512, 512, 512, 512, 512);
  gemm64<false, false, false><<<dim3(8, 32), 256, 0, stream>>>(
      W_ih, Wo, Wcomb, nullptr, 2048, 512, 512, 640, 512, 1152);
  wcomb_copy<<<5120, 256, 0, stream>>>(W_hh, W_ih, Wcomb);
  biasg_kernel<<<8, 256, 0, stream>>>(W_ih, b_ih, b_hh, bo, ws + biasg_off);
  reorderW<<<dim3(8, 1152), 256, 0, stream>>>(Wcomb, ws + WcombT_off);
  reorderB<<<8, 256, 0, stream>>>(ws + biasg_off, ws + biasg2_off);
  transposeT<<<2048, 256, 0, stream>>>(tgt, ws + tgtT_off);
  svec_kernel<<<128, 256, 0, stream>>>(memory, ws + wb_off, ws + dotc_off, ws + svec_off);

  // ---- all 64 recurrent steps, one persistent kernel ----
  step_loop<<<512, 256, 0, stream>>>(K2T, Vv, ws + svec_off, ws + WcombT_off,
                                     ws + biasg2_off, ws + tgtT_off, Wcls, bcls,
                                     h0, ws + h1_off, hT0, ws + hT1_off,
                                     ws + ctxT_off, ws + mlval_off,
                                     mlcnt, gcnt, flags, gosig,
                                     gpart, out);
}

// Round 4
// 6425.386 us; speedup vs baseline: 1.2049x; 1.2049x over previous
//
#include <hip/hip_runtime.h>
#include <hip/hip_bf16.h>

// B=64, S=512, T=64, E=H=512, V=128, G=4H=2048, Kgates=1152
// Persistent kernel (512 blocks, 2/CU), 2 grid barriers/step.
// R4: NO acquire fences / cache invalidations inside the loop. All mutable
// cross-block data goes through device-scope atomics (bypass L2 -> coherence
// point); read-only arrays (K2T,V,WcombT,tgtT,...) use plain cached loads and
// stay resident in L2/L3 across steps.

#define DI __device__ __forceinline__
typedef __hip_bfloat16 bf16;
typedef __hip_bfloat162 bf162;

#define AGENT __HIP_MEMORY_SCOPE_AGENT
DI float aload(const float* p) {
  return __hip_atomic_load(p, __ATOMIC_RELAXED, AGENT);
}
DI void astore(float* p, float v) {
  __hip_atomic_store(p, v, __ATOMIC_RELAXED, AGENT);
}
DI unsigned uload(const unsigned* p) {
  return __hip_atomic_load(p, __ATOMIC_RELAXED, AGENT);
}
DI float2 bf2f2(unsigned int u) {
  bf162 b = *reinterpret_cast<const bf162*>(&u);
  return __bfloat1622float2(b);
}
DI float sigm(float x) { return 1.f / (1.f + expf(-x)); }

// ---------------------------------------------------------------------------
// Generic 64x64-tile fp32 GEMM (precompute only).
// ---------------------------------------------------------------------------
template<bool BT, bool OBF, bool CT>
__launch_bounds__(256)
__global__ void gemm64(const float* __restrict__ A, const float* __restrict__ Bm,
                       void* __restrict__ Cp, const float* __restrict__ bias,
                       int M, int N, int K, int lda, int ldb, int ldc) {
  __shared__ __align__(16) float As[16][68];
  __shared__ __align__(16) float Bs[16][68];
  const int tid = threadIdx.x;
  const int n0 = blockIdx.x * 64;
  const int m0 = blockIdx.y * 64;
  const int tx = tid & 15, ty = tid >> 4;
  const int arow = tid >> 2;
  const int acol = (tid & 3) * 4;
  float acc[4][4] = {};
  for (int k0 = 0; k0 < K; k0 += 16) {
    float4 a4 = *(const float4*)&A[(size_t)(m0 + arow) * lda + k0 + acol];
    As[acol + 0][arow] = a4.x; As[acol + 1][arow] = a4.y;
    As[acol + 2][arow] = a4.z; As[acol + 3][arow] = a4.w;
    if (BT) {
      float4 b4 = *(const float4*)&Bm[(size_t)(n0 + arow) * ldb + k0 + acol];
      Bs[acol + 0][arow] = b4.x; Bs[acol + 1][arow] = b4.y;
      Bs[acol + 2][arow] = b4.z; Bs[acol + 3][arow] = b4.w;
    } else {
      const int brow = tid >> 4;
      const int bcol = (tid & 15) * 4;
      float4 b4 = *(const float4*)&Bm[(size_t)(k0 + brow) * ldb + n0 + bcol];
      *(float4*)&Bs[brow][bcol] = b4;
    }
    __syncthreads();
#pragma unroll
    for (int kk = 0; kk < 16; kk++) {
      float4 av = *(const float4*)&As[kk][ty * 4];
      float4 bv = *(const float4*)&Bs[kk][tx * 4];
      float a_[4] = {av.x, av.y, av.z, av.w};
      float b_[4] = {bv.x, bv.y, bv.z, bv.w};
#pragma unroll
      for (int i = 0; i < 4; i++)
#pragma unroll
        for (int j = 0; j < 4; j++) acc[i][j] += a_[i] * b_[j];
    }
    __syncthreads();
  }
#pragma unroll
  for (int i = 0; i < 4; i++) {
    const int m = m0 + ty * 4 + i;
#pragma unroll
    for (int j = 0; j < 4; j++) {
      const int n = n0 + tx * 4 + j;
      float v = acc[i][j] + (bias ? bias[n] : 0.f);
      if (OBF) {
        if (CT) {
          int bb = m >> 9, sE = m & 511;
          ((bf16*)Cp)[((size_t)bb << 18) + (size_t)n * 512 + sE] = __float2bfloat16(v);
        } else {
          ((bf16*)Cp)[(size_t)m * ldc + n] = __float2bfloat16(v);
        }
      } else {
        ((float*)Cp)[(size_t)m * ldc + n] = v;
      }
    }
  }
}

// ---------------------------------------------------------------------------
// Small precompute kernels
// ---------------------------------------------------------------------------
__launch_bounds__(256)
__global__ void transpose512(const float* __restrict__ src, float* __restrict__ dst) {
  int idx = blockIdx.x * 256 + threadIdx.x;
  int r = idx >> 9, c = idx & 511;
  dst[(size_t)c * 512 + r] = src[idx];
}

__launch_bounds__(256)
__global__ void colvec_kernel(const float* __restrict__ bvec, const float* __restrict__ W,
                              float* __restrict__ outv) {
  int e = blockIdx.x * 256 + threadIdx.x;
  float acc = 0.f;
  for (int f = 0; f < 512; f++) acc += bvec[f] * W[(size_t)f * 512 + e];
  outv[e] = acc;
}

__launch_bounds__(256)
__global__ void dot_kernel(const float* __restrict__ a, const float* __restrict__ b,
                           float* __restrict__ outp) {
  __shared__ float red[256];
  int tid = threadIdx.x;
  red[tid] = a[tid] * b[tid] + a[tid + 256] * b[tid + 256];
  __syncthreads();
  for (int st = 128; st > 0; st >>= 1) {
    if (tid < st) red[tid] += red[tid + st];
    __syncthreads();
  }
  if (tid == 0) *outp = red[0];
}

__launch_bounds__(256)
__global__ void svec_kernel(const float* __restrict__ mem, const float* __restrict__ wb,
                            const float* __restrict__ dotc, float* __restrict__ svec) {
  __shared__ __align__(16) float ws_[512];
  int tid = threadIdx.x;
  *(float2*)&ws_[tid * 2] = *(const float2*)&wb[tid * 2];
  __syncthreads();
  int bs = blockIdx.x * 256 + tid;
  const float4* mr = (const float4*)&mem[(size_t)bs * 512];
  const float4* w4 = (const float4*)ws_;
  float acc = *dotc;
#pragma unroll 4
  for (int j = 0; j < 128; j++) {
    float4 m = mr[j], w = w4[j];
    acc += m.x * w.x + m.y * w.y + m.z * w.z + m.w * w.w;
  }
  svec[bs] = acc;
}

__launch_bounds__(256)
__global__ void biasg_kernel(const float* __restrict__ W_ih, const float* __restrict__ b_ih,
                             const float* __restrict__ b_hh, const float* __restrict__ bo,
                             float* __restrict__ biasg) {
  int j = blockIdx.x * 256 + threadIdx.x;
  float acc = b_ih[j] + b_hh[j];
  const float4* wr = (const float4*)&W_ih[(size_t)j * 640];
  const float4* br = (const float4*)bo;
#pragma unroll 4
  for (int f4 = 0; f4 < 128; f4++) {
    float4 w = wr[f4], bb = br[f4];
    acc += w.x * bb.x + w.y * bb.y + w.z * bb.z + w.w * bb.w;
  }
  biasg[j] = acc;
}

__launch_bounds__(256)
__global__ void wcomb_copy(const float* __restrict__ W_hh, const float* __restrict__ W_ih,
                           float* __restrict__ Wcomb) {
  int idx = blockIdx.x * 256 + threadIdx.x;
  int j = idx / 640, cc = idx % 640;
  float v = (cc < 512) ? W_hh[(size_t)j * 512 + cc] : W_ih[(size_t)j * 640 + cc];
  Wcomb[(size_t)j * 1152 + 512 + cc] = v;
}

// WcombT[k][j'=d*4+g] = Wcomb[g*512+d][k]   (gate-interleaved, k-major)
__launch_bounds__(256)
__global__ void reorderW(const float* __restrict__ Wc, float* __restrict__ WcT) {
  int jp = blockIdx.x * 256 + threadIdx.x;
  int k  = blockIdx.y;
  WcT[(size_t)k * 2048 + jp] = Wc[((size_t)(jp & 3) * 512 + (jp >> 2)) * 1152 + k];
}

__launch_bounds__(256)
__global__ void reorderB(const float* __restrict__ bg, float* __restrict__ bg2) {
  int jp = blockIdx.x * 256 + threadIdx.x;
  bg2[jp] = bg[(size_t)(jp & 3) * 512 + (jp >> 2)];
}

// tgtT[t][v][b] = tgt[b][t][v]
__launch_bounds__(256)
__global__ void transposeT(const float* __restrict__ tg, float* __restrict__ tgT) {
  int idx = blockIdx.x * 256 + threadIdx.x;
  int b = idx & 63, tv = idx >> 6;
  int t = tv >> 7, v = tv & 127;
  tgT[idx] = tg[((size_t)b * 64 + t) * 128 + v];
}

// ---------------------------------------------------------------------------
// Persistent step-loop: 512 blocks x 256 threads, 2 grid barriers / step.
// ---------------------------------------------------------------------------
struct SMemA { float hs[512]; float buf[2112]; float p[64]; float red[4]; };
struct SMemB { __align__(16) float As[144][68]; __align__(16) float Bs[144][36]; };
union SMemU { SMemA a; SMemB b; };   // 59904 B -> 2 blocks/CU

// Barrier with NO cache invalidation: release on arrive-flag publishes prior
// atomic writes; consumers use device-scope atomic loads (bypass L2) so no
// acquire/invalidate is needed. Compiler barrier stops load hoisting.
DI void gbar(unsigned* flags, unsigned* gosig, int slot) {
  const unsigned tgt = (unsigned)slot + 1u;
  __syncthreads();
  if (threadIdx.x == 0)
    __hip_atomic_store(&flags[blockIdx.x], tgt, __ATOMIC_RELEASE, AGENT);
  if (blockIdx.x == 0) {
    while (uload(&flags[threadIdx.x]) < tgt || uload(&flags[threadIdx.x + 256]) < tgt)
      __builtin_amdgcn_s_sleep(2);
    __syncthreads();
    if (threadIdx.x == 0)
      __hip_atomic_store(gosig, tgt, __ATOMIC_RELEASE, AGENT);
  }
  if (threadIdx.x == 0) {
    while (uload(gosig) < tgt)
      __builtin_amdgcn_s_sleep(2);
  }
  __asm__ __volatile__("" ::: "memory");
  __syncthreads();
}

__launch_bounds__(256, 2)
__global__ void step_loop(const bf16* __restrict__ K2T, const bf16* __restrict__ Vv,
                          const float* __restrict__ svec, const float* __restrict__ WcombT,
                          const float* __restrict__ biasg2, const float* __restrict__ tgtT,
                          const float* __restrict__ Wcls, const float* __restrict__ bcls,
                          float* __restrict__ hA, float* __restrict__ hB,
                          float* __restrict__ hTA, float* __restrict__ hTB,
                          float* __restrict__ ctxT, float* __restrict__ mlval,
                          unsigned* mlcnt, unsigned* gcnt, unsigned* flags, unsigned* gosig,
                          float* __restrict__ gpart, float* __restrict__ out) {
  __shared__ SMemU sm;
  const int blk = blockIdx.x, tid = threadIdx.x;
  const int b = blk >> 3, jj = blk & 7, s0 = jj * 64;   // phase A role
  const int ks = blk >> 6, nc = blk & 63;               // phase B role
  const float SCALE = 0.04419417382415922f;             // 1/sqrt(512)
  float cval = 0.f;                                     // register-resident c
  int slot = 0;

  for (int t = 0; t <= 64; t++) {
    const float* hR  = (t & 1) ? hB : hA;
    const float* hTR = (t & 1) ? hTB : hTA;
    float* hW  = (t & 1) ? hA : hB;
    float* hTW = (t & 1) ? hTA : hTB;

    // ---- load h into LDS (h is mutable cross-block -> atomic loads) ----
    sm.a.hs[2 * tid]     = aload(&hR[(size_t)b * 512 + 2 * tid]);
    sm.a.hs[2 * tid + 1] = aload(&hR[(size_t)b * 512 + 2 * tid + 1]);
    __syncthreads();

    // ---- classifier: out[t-1] (16 v's per block) ----
    if (t > 0) {
      const int v = jj * 16 + (tid >> 4), part = tid & 15;
      const float4* wr = (const float4*)&Wcls[(size_t)v * 512 + part * 32];
      const float4* hr = (const float4*)&sm.a.hs[part * 32];
      float a = 0.f;
#pragma unroll
      for (int q = 0; q < 8; q++) {
        float4 w = wr[q], x = hr[q];
        a += w.x * x.x + w.y * x.y + w.z * x.z + w.w * x.w;
      }
      a += __shfl_xor(a, 1); a += __shfl_xor(a, 2);
      a += __shfl_xor(a, 4); a += __shfl_xor(a, 8);
      if (part == 0) out[((size_t)b * 64 + (t - 1)) * 128 + v] = a + bcls[v];
    }
    if (t == 64) return;

    // ================= PHASE A: attention (8 blocks per b) =================
    if (tid < 64)
      astore(&ctxT[(size_t)(jj * 64 + tid) * 64 + b], 0.f);
    // scores partials: eg = tid>>3 covers 16 e's, sg = tid&7 covers 8 s's
    {
      const int eg = tid >> 3, sg = tid & 7;
      float a8[8] = {};
      const uint4* kp = (const uint4*)&K2T[((size_t)b << 18) + (size_t)(eg * 16) * 512 + s0 + 8 * sg];
#pragma unroll 8
      for (int i = 0; i < 16; i++) {
        uint4 q = kp[(size_t)i * 64];
        float he = sm.a.hs[eg * 16 + i];
        float2 p0 = bf2f2(q.x), p1 = bf2f2(q.y), p2 = bf2f2(q.z), p3 = bf2f2(q.w);
        a8[0] += he * p0.x; a8[1] += he * p0.y; a8[2] += he * p1.x; a8[3] += he * p1.y;
        a8[4] += he * p2.x; a8[5] += he * p2.y; a8[6] += he * p3.x; a8[7] += he * p3.y;
      }
#pragma unroll
      for (int y = 0; y < 8; y++) sm.a.buf[eg * 66 + sg * 8 + y] = a8[y];
    }
    __syncthreads();   // S1
    if (tid < 64) {
      float sv = 0.f;
#pragma unroll
      for (int eg = 0; eg < 32; eg++) sv += sm.a.buf[eg * 66 + tid];
      float pvl = (sv + svec[(size_t)b * 512 + s0 + tid]) * SCALE;
      float mv = pvl;
#pragma unroll
      for (int off = 32; off; off >>= 1) mv = fmaxf(mv, __shfl_xor(mv, off));
      float evl = __expf(pvl - mv);
      sm.a.p[tid] = evl;
      float lv = evl;
#pragma unroll
      for (int off = 32; off; off >>= 1) lv += __shfl_xor(lv, off);
      if (tid == 0) { sm.a.red[0] = mv; sm.a.red[1] = lv; }
    }
    __syncthreads();   // S2
    if (tid == 0) {
      astore(&mlval[((size_t)b * 8 + jj) * 2 + 0], sm.a.red[0]);
      astore(&mlval[((size_t)b * 8 + jj) * 2 + 1], sm.a.red[1]);
      // RELEASE add publishes ctxT-zero + mlval stores (waitcnt, no invalidate)
      __hip_atomic_fetch_add(&mlcnt[b], 1u, __ATOMIC_RELEASE, AGENT);
    }
    // ctx partials: wave w covers 16 s's, lane l covers e = 8l..8l+7
    {
      const int w = tid >> 6, l = tid & 63;
      float c8[8] = {};
      const uint4* vp = (const uint4*)&Vv[((size_t)b << 18) + (size_t)(s0 + w * 16) * 512 + 8 * l];
#pragma unroll 8
      for (int i = 0; i < 16; i++) {
        float ps = sm.a.p[w * 16 + i];
        uint4 q = vp[(size_t)i * 64];
        float2 p0 = bf2f2(q.x), p1 = bf2f2(q.y), p2 = bf2f2(q.z), p3 = bf2f2(q.w);
        c8[0] += ps * p0.x; c8[1] += ps * p0.y; c8[2] += ps * p1.x; c8[3] += ps * p1.y;
        c8[4] += ps * p2.x; c8[5] += ps * p2.y; c8[6] += ps * p3.x; c8[7] += ps * p3.y;
      }
      *(float4*)&sm.a.buf[w * 520 + 8 * l]     = make_float4(c8[0], c8[1], c8[2], c8[3]);
      *(float4*)&sm.a.buf[w * 520 + 8 * l + 4] = make_float4(c8[4], c8[5], c8[6], c8[7]);
    }
    __syncthreads();   // S3
    if (tid == 0) {
      while (uload(&mlcnt[b]) < 8u * (t + 1))
        __builtin_amdgcn_s_sleep(1);
      __asm__ __volatile__("" ::: "memory");
      float mj[8], lj[8], M = -1e30f;
#pragma unroll
      for (int q = 0; q < 8; q++) {
        mj[q] = aload(&mlval[((size_t)b * 8 + q) * 2 + 0]);
        lj[q] = aload(&mlval[((size_t)b * 8 + q) * 2 + 1]);
        M = fmaxf(M, mj[q]);
      }
      float L = 0.f;
#pragma unroll
      for (int q = 0; q < 8; q++) L += __expf(mj[q] - M) * lj[q];
      sm.a.red[2] = __expf(mj[jj] - M) / L;
    }
    __syncthreads();   // S4
    {
      const float msc = sm.a.red[2];
      float cx = sm.a.buf[tid] + sm.a.buf[520 + tid] + sm.a.buf[1040 + tid] + sm.a.buf[1560 + tid];
      float cy = sm.a.buf[tid + 256] + sm.a.buf[520 + tid + 256] +
                 sm.a.buf[1040 + tid + 256] + sm.a.buf[1560 + tid + 256];
      atomicAdd(&ctxT[(size_t)tid * 64 + b], cx * msc);
      atomicAdd(&ctxT[(size_t)(tid + 256) * 64 + b], cy * msc);
    }
    gbar(flags, gosig, slot++);

    // ====== PHASE B+C: gates GEMM (8 ks x 64 nc) + fused reduce + cell ======
    {
      const int k0 = ks * 144;
      for (int q = tid; q < 2304; q += 256) {
        const int row = q >> 4, c4 = (q & 15) * 4;
        const int k = k0 + row;
        if (k < 512) {
          sm.b.As[row][c4 + 0] = aload(&ctxT[(size_t)k * 64 + c4 + 0]);
          sm.b.As[row][c4 + 1] = aload(&ctxT[(size_t)k * 64 + c4 + 1]);
          sm.b.As[row][c4 + 2] = aload(&ctxT[(size_t)k * 64 + c4 + 2]);
          sm.b.As[row][c4 + 3] = aload(&ctxT[(size_t)k * 64 + c4 + 3]);
        } else if (k < 1024) {
          sm.b.As[row][c4 + 0] = aload(&hTR[(size_t)(k - 512) * 64 + c4 + 0]);
          sm.b.As[row][c4 + 1] = aload(&hTR[(size_t)(k - 512) * 64 + c4 + 1]);
          sm.b.As[row][c4 + 2] = aload(&hTR[(size_t)(k - 512) * 64 + c4 + 2]);
          sm.b.As[row][c4 + 3] = aload(&hTR[(size_t)(k - 512) * 64 + c4 + 3]);
        } else {
          float4 xv = *(const float4*)&tgtT[((size_t)t * 128 + (k - 1024)) * 64 + c4];
          *(float4*)&sm.b.As[row][c4] = xv;
        }
      }
      for (int q = tid; q < 1152; q += 256) {
        const int row = q >> 3, c4 = (q & 7) * 4;
        *(float4*)&sm.b.Bs[row][c4] = *(const float4*)&WcombT[(size_t)(k0 + row) * 2048 + nc * 32 + c4];
      }
      __syncthreads();
      const int tx = tid & 7, ty = tid >> 3;
      float acc[2][4] = {};
#pragma unroll 4
      for (int kk = 0; kk < 144; kk++) {
        float2 av = *(const float2*)&sm.b.As[kk][ty * 2];
        float4 bv = *(const float4*)&sm.b.Bs[kk][tx * 4];
        acc[0][0] += av.x * bv.x; acc[0][1] += av.x * bv.y;
        acc[0][2] += av.x * bv.z; acc[0][3] += av.x * bv.w;
        acc[1][0] += av.y * bv.x; acc[1][1] += av.y * bv.y;
        acc[1][2] += av.y * bv.z; acc[1][3] += av.y * bv.w;
      }
#pragma unroll
      for (int i = 0; i < 2; i++) {
        const size_t gp = ((size_t)ks * 64 + ty * 2 + i) * 2048 + nc * 32 + tx * 4;
        astore(&gpart[gp + 0], acc[i][0]);
        astore(&gpart[gp + 1], acc[i][1]);
        astore(&gpart[gp + 2], acc[i][2]);
        astore(&gpart[gp + 3], acc[i][3]);
      }
    }
    __syncthreads();
    if (tid == 0) {
      __hip_atomic_fetch_add(&gcnt[nc], 1u, __ATOMIC_RELEASE, AGENT);
      while (uload(&gcnt[nc]) < 8u * (t + 1))
        __builtin_amdgcn_s_sleep(1);
    }
    __asm__ __volatile__("" ::: "memory");
    __syncthreads();
    {
      // reduce slice: b in [ks*8, ks*8+8), cols nc*32..nc*32+31
      const int bb = ks * 8 + (tid >> 5);
      const int col = tid & 31;
      const int d = nc * 8 + ((tid >> 2) & 7);
      float val = biasg2[nc * 32 + col];
#pragma unroll
      for (int k2 = 0; k2 < 8; k2++)
        val += aload(&gpart[((size_t)k2 * 64 + bb) * 2048 + nc * 32 + col]);
      const int qbase = (tid & 63) & ~3;
      float gi = __shfl(val, qbase + 0);
      float gf = __shfl(val, qbase + 1);
      float gg = __shfl(val, qbase + 2);
      float go_ = __shfl(val, qbase + 3);
      float cn = sigm(gf) * cval + sigm(gi) * tanhf(gg);
      cval = cn;
      float hn = sigm(go_) * tanhf(cn);
      const int g = tid & 3;
      if (g == 0)      astore(&hW[(size_t)bb * 512 + d], hn);
      else if (g == 1) astore(&hTW[(size_t)d * 64 + bb], hn);
    }
    gbar(flags, gosig, slot++);
  }
}

// ---------------------------------------------------------------------------
extern "C" void kernel_launch(void* const* d_in, const int* in_sizes, int n_in,
                              void* d_out, int out_size, void* d_ws, size_t ws_size,
                              hipStream_t stream) {
  const float* memory = (const float*)d_in[0];
  const float* tgt    = (const float*)d_in[1];
  const float* Wq     = (const float*)d_in[2];
  const float* bq     = (const float*)d_in[3];
  const float* Wk     = (const float*)d_in[4];
  const float* bk     = (const float*)d_in[5];
  const float* Wv     = (const float*)d_in[6];
  const float* bv     = (const float*)d_in[7];
  const float* Wo     = (const float*)d_in[8];
  const float* bo     = (const float*)d_in[9];
  const float* W_ih   = (const float*)d_in[10];
  const float* b_ih   = (const float*)d_in[11];
  const float* W_hh   = (const float*)d_in[12];
  const float* b_hh   = (const float*)d_in[13];
  const float* Wcls   = (const float*)d_in[14];
  const float* bcls   = (const float*)d_in[15];
  float* out = (float*)d_out;

  float* ws = (float*)d_ws;
  size_t off = 0;
  auto alloc = [&](size_t n) { size_t r = off; off += (n + 15) & ~(size_t)15; return r; };
  const size_t K2_off     = alloc(8388608);   // bf16 x16.7M: K2T [b][e][s]
  const size_t V_off      = alloc(8388608);   // bf16 x16.7M: V   [b][s][e]
  const size_t WcombT_off = alloc(2359296);   // fp32 [k][j'] 1152x2048
  const size_t svec_off   = alloc(32768);
  const size_t sb_off     = alloc(512);
  const size_t wb_off     = alloc(512);
  const size_t dotc_off   = alloc(16);
  const size_t biasg_off  = alloc(2048);
  const size_t biasg2_off = alloc(2048);
  const size_t tgtT_off   = alloc(524288);    // [t][v][b]
  const size_t zero_off   = alloc(67584);     // h0(32768) hT0(32768) sync(2048)
  const size_t h1_off     = alloc(32768);
  const size_t hT1_off    = alloc(32768);
  const size_t ctxT_off   = alloc(32768);     // [e][b]
  const size_t mlval_off  = alloc(1024);
  const size_t scr_off    = alloc(2883584);   // precompute: Wcomb+Wkq+WkT / loop: gpart

  bf16* K2T = (bf16*)(ws + K2_off);
  bf16* Vv  = (bf16*)(ws + V_off);
  float* h0   = ws + zero_off;
  float* hT0  = h0 + 32768;
  unsigned* sync = (unsigned*)(hT0 + 32768);
  unsigned* flags = sync;            // 512
  unsigned* gosig = sync + 512;      // 1
  unsigned* mlcnt = sync + 576;      // 64
  unsigned* gcnt  = sync + 640;      // 64
  float* Wcomb = ws + scr_off;                // precompute phase
  float* Wkq   = Wcomb + 2359296;
  float* WkT   = Wkq + 262144;
  float* gpart = ws + scr_off;                // loop phase (overlaps Wcomb)

  hipMemsetAsync(h0, 0, 67584 * sizeof(float), stream);

  // ---- precompute (step-invariant) ----
  transpose512<<<1024, 256, 0, stream>>>(Wk, WkT);
  colvec_kernel<<<2, 256, 0, stream>>>(bk, Wq, ws + sb_off);
  colvec_kernel<<<2, 256, 0, stream>>>(bq, Wk, ws + wb_off);
  dot_kernel<<<1, 256, 0, stream>>>(bq, bk, ws + dotc_off);
  gemm64<false, false, false><<<dim3(8, 8), 256, 0, stream>>>(
      WkT, Wq, Wkq, nullptr, 512, 512, 512, 512, 512, 512);
  gemm64<false, true, true><<<dim3(8, 512), 256, 0, stream>>>(
      memory, Wkq, K2T, ws + sb_off, 32768, 512, 512, 512, 512, 512);
  gemm64<true, true, false><<<dim3(8, 512), 256, 0, stream>>>(
      memory, Wv, Vv, bv, 32768, 512, 512, 512, 512, 512);
  gemm64<false, false, false><<<dim3(8, 32), 256, 0, stream>>>(
      W_ih, Wo, Wcomb, nullptr, 2048, 512, 512, 640, 512, 1152);
  wcomb_copy<<<5120, 256, 0, stream>>>(W_hh, W_ih, Wcomb);
  biasg_kernel<<<8, 256, 0, stream>>>(W_ih, b_ih, b_hh, bo, ws + biasg_off);
  reorderW<<<dim3(8, 1152), 256, 0, stream>>>(Wcomb, ws + WcombT_off);
  reorderB<<<8, 256, 0, stream>>>(ws + biasg_off, ws + biasg2_off);
  transposeT<<<2048, 256, 0, stream>>>(tgt, ws + tgtT_off);
  svec_kernel<<<128, 256, 0, stream>>>(memory, ws + wb_off, ws + dotc_off, ws + svec_off);

  // ---- all 64 recurrent steps, one persistent kernel ----
  step_loop<<<512, 256, 0, stream>>>(K2T, Vv, ws + svec_off, ws + WcombT_off,
                                     ws + biasg2_off, ws + tgtT_off, Wcls, bcls,
                                     h0, ws + h1_off, hT0, ws + hT1_off,
                                     ws + ctxT_off, ws + mlval_off,
                                     mlcnt, gcnt, flags, gosig,
                                     gpart, out);
}

// Round 5
// 4895.556 us; speedup vs baseline: 1.5814x; 1.3125x over previous
//
#include <hip/hip_runtime.h>
#include <hip/hip_bf16.h>

// B=64, S=512, T=64, E=H=512, V=128, G=2048, Kgates=1152
// R5: mem-only attention (scores = q2·mem, u = attn·mem, Wv/Wo folded into
// gates weights), no-max softmax with deferred normalization (no softmax
// merge sub-barrier), 3 clean grid barriers/step with 128B-padded per-block
// flags (no shared-line polling hotspots). Read-only working set is XCD-L2
// resident; mutable cross-block data via device-scope atomics (L2 bypass).

#define DI __device__ __forceinline__
typedef __hip_bfloat16 bf16;
typedef __hip_bfloat162 bf162;
#define AGENT __HIP_MEMORY_SCOPE_AGENT

DI float aload(const float* p) { return __hip_atomic_load(p, __ATOMIC_RELAXED, AGENT); }
DI void astore(float* p, float v) { __hip_atomic_store(p, v, __ATOMIC_RELAXED, AGENT); }
DI unsigned uload(const unsigned* p) { return __hip_atomic_load(p, __ATOMIC_RELAXED, AGENT); }
DI float2 bf2f2(unsigned u) { bf162 b = *reinterpret_cast<const bf162*>(&u); return __bfloat1622float2(b); }
DI float sigm(float x) { return 1.f / (1.f + expf(-x)); }

// ---------------------------------------------------------------------------
// Plain fp32 64x64 GEMM (precompute only): C = A(MxK,lda) @ B(KxN,ldb)
// ---------------------------------------------------------------------------
__launch_bounds__(256)
__global__ void gemm64(const float* __restrict__ A, const float* __restrict__ Bm,
                       float* __restrict__ C, int M, int N, int K,
                       int lda, int ldb, int ldc) {
  __shared__ __align__(16) float As[16][68];
  __shared__ __align__(16) float Bs[16][68];
  const int tid = threadIdx.x;
  const int n0 = blockIdx.x * 64, m0 = blockIdx.y * 64;
  const int tx = tid & 15, ty = tid >> 4;
  const int arow = tid >> 2, acol = (tid & 3) * 4;
  float acc[4][4] = {};
  for (int k0 = 0; k0 < K; k0 += 16) {
    float4 a4 = *(const float4*)&A[(size_t)(m0 + arow) * lda + k0 + acol];
    As[acol + 0][arow] = a4.x; As[acol + 1][arow] = a4.y;
    As[acol + 2][arow] = a4.z; As[acol + 3][arow] = a4.w;
    {
      const int brow = tid >> 4, bcol = (tid & 15) * 4;
      float4 b4 = *(const float4*)&Bm[(size_t)(k0 + brow) * ldb + n0 + bcol];
      *(float4*)&Bs[brow][bcol] = b4;
    }
    __syncthreads();
#pragma unroll
    for (int kk = 0; kk < 16; kk++) {
      float4 av = *(const float4*)&As[kk][ty * 4];
      float4 bv = *(const float4*)&Bs[kk][tx * 4];
      float a_[4] = {av.x, av.y, av.z, av.w};
      float b_[4] = {bv.x, bv.y, bv.z, bv.w};
#pragma unroll
      for (int i = 0; i < 4; i++)
#pragma unroll
        for (int j = 0; j < 4; j++) acc[i][j] += a_[i] * b_[j];
    }
    __syncthreads();
  }
#pragma unroll
  for (int i = 0; i < 4; i++)
#pragma unroll
    for (int j = 0; j < 4; j++)
      C[(size_t)(m0 + ty * 4 + i) * ldc + n0 + tx * 4 + j] = acc[i][j];
}

// ---------------------------------------------------------------------------
// Precompute kernels
// ---------------------------------------------------------------------------
__launch_bounds__(256)
__global__ void cast_mem(const float* __restrict__ src, bf16* __restrict__ dst) {
  size_t i = ((size_t)blockIdx.x * 256 + threadIdx.x) * 8;
  float4 a = *(const float4*)&src[i];
  float4 b = *(const float4*)&src[i + 4];
  bf16 o[8] = {__float2bfloat16(a.x), __float2bfloat16(a.y), __float2bfloat16(a.z),
               __float2bfloat16(a.w), __float2bfloat16(b.x), __float2bfloat16(b.y),
               __float2bfloat16(b.z), __float2bfloat16(b.w)};
  *(uint4*)&dst[i] = *(const uint4*)o;
}

__launch_bounds__(256)
__global__ void transpose512(const float* __restrict__ src, float* __restrict__ dst) {
  int idx = blockIdx.x * 256 + threadIdx.x;
  int r = idx >> 9, c = idx & 511;
  dst[(size_t)c * 512 + r] = src[idx];
}

// outv[e] = sum_f bvec[f] * W[f*512 + e]
__launch_bounds__(256)
__global__ void colvec_kernel(const float* __restrict__ bvec, const float* __restrict__ W,
                              float* __restrict__ outv) {
  int e = blockIdx.x * 256 + threadIdx.x;
  float acc = 0.f;
  for (int f = 0; f < 512; f++) acc += bvec[f] * W[(size_t)f * 512 + e];
  outv[e] = acc;
}

// bvo[a] = sum_x bv[x]*Wo[a][x] + bo[a]
__launch_bounds__(256)
__global__ void bvo_kernel(const float* __restrict__ bv, const float* __restrict__ Wo,
                           const float* __restrict__ bo, float* __restrict__ bvo) {
  int a = blockIdx.x * 256 + threadIdx.x;
  float acc = bo[a];
  const float4* wr = (const float4*)&Wo[(size_t)a * 512];
  const float4* br = (const float4*)bv;
#pragma unroll 4
  for (int x4 = 0; x4 < 128; x4++) {
    float4 w = wr[x4], bb = br[x4];
    acc += w.x * bb.x + w.y * bb.y + w.z * bb.z + w.w * bb.w;
  }
  bvo[a] = acc;
}

// biasg[j] = b_ih[j] + b_hh[j] + sum_f bvo[f]*W_ih[j,f]  (f<512, lda 640)
__launch_bounds__(256)
__global__ void biasg_kernel(const float* __restrict__ W_ih, const float* __restrict__ b_ih,
                             const float* __restrict__ b_hh, const float* __restrict__ bvo,
                             float* __restrict__ biasg) {
  int j = blockIdx.x * 256 + threadIdx.x;
  float acc = b_ih[j] + b_hh[j];
  const float4* wr = (const float4*)&W_ih[(size_t)j * 640];
  const float4* br = (const float4*)bvo;
#pragma unroll 4
  for (int f4 = 0; f4 < 128; f4++) {
    float4 w = wr[f4], bb = br[f4];
    acc += w.x * bb.x + w.y * bb.y + w.z * bb.z + w.w * bb.w;
  }
  biasg[j] = acc;
}

__launch_bounds__(256)
__global__ void reorderB(const float* __restrict__ bg, float* __restrict__ bg2) {
  int jp = blockIdx.x * 256 + threadIdx.x;
  bg2[jp] = bg[(size_t)(jp & 3) * 512 + (jp >> 2)];
}

// tgtT[t][v][b] = tgt[b][t][v]
__launch_bounds__(256)
__global__ void transposeT(const float* __restrict__ tg, float* __restrict__ tgT) {
  int idx = blockIdx.x * 256 + threadIdx.x;
  int b = idx & 63, tv = idx >> 6;
  int t = tv >> 7, v = tv & 127;
  tgT[idx] = tg[((size_t)b * 64 + t) * 128 + v];
}

// W0[n][k] (640x512): n<512 -> A[k][n]*SCALE ; else Wcls[n-512][k].
// bias0[n]: n<512 -> c0[n]*SCALE ; else bcls[n-512].
__launch_bounds__(256)
__global__ void assembleW0(const float* __restrict__ A, const float* __restrict__ Wcls,
                           const float* __restrict__ c0, const float* __restrict__ bcls,
                           float* __restrict__ W0, float* __restrict__ bias0) {
  const float SCALE = 0.04419417382415922f;
  int idx = blockIdx.x * 256 + threadIdx.x;   // < 640*512
  int n = idx >> 9, k = idx & 511;
  W0[idx] = (n < 512) ? A[(size_t)k * 512 + n] * SCALE : Wcls[(size_t)(n - 512) * 512 + k];
  if (k == 0) bias0[n] = (n < 512) ? c0[n] * SCALE : bcls[n - 512];
}

// Wg[k][j'=d*4+g] (1152x2048): k<512 -> U2[j][k]; k<1024 -> W_hh[j][k-512];
// else W_ih[j][512+(k-1024)] (lda 640), with j = g*512+d.
__launch_bounds__(256)
__global__ void assembleWg(const float* __restrict__ U2, const float* __restrict__ W_hh,
                           const float* __restrict__ W_ih, float* __restrict__ Wg) {
  int idx = blockIdx.x * 256 + threadIdx.x;   // < 1152*2048
  int k = idx >> 11, jp = idx & 2047;
  int d = jp >> 2, g = jp & 3, j = g * 512 + d;
  float v;
  if (k < 512)       v = U2[(size_t)j * 512 + k];
  else if (k < 1024) v = W_hh[(size_t)j * 512 + (k - 512)];
  else               v = W_ih[(size_t)j * 640 + 512 + (k - 1024)];
  Wg[idx] = v;
}

// ---------------------------------------------------------------------------
// Persistent step loop: 512 blocks x 256 threads, 3 barriers/step.
// ---------------------------------------------------------------------------
struct SMemA { float q2L[512]; float sp[1024]; float p[64]; float buf[2080]; };
struct SMemB { float rL[64]; __align__(16) float As[144][68]; __align__(16) float Bs[144][36]; };
union SMemU { SMemA a; SMemB b; };   // 60416 B -> 2 blocks/CU

// flags/go: one 128B line per block (stride 32 uints). No shared-line polling.
DI void gbar(unsigned* flags, unsigned* go, int slot) {
  const unsigned tgt = (unsigned)slot + 1u;
  const int tid = threadIdx.x, blk = blockIdx.x;
  __syncthreads();
  if (tid == 0)
    __hip_atomic_store(&flags[blk * 32], tgt, __ATOMIC_RELEASE, AGENT);
  if (blk == 0) {
    while (uload(&flags[tid * 32]) < tgt || uload(&flags[(tid + 256) * 32]) < tgt)
      __builtin_amdgcn_s_sleep(1);
    __syncthreads();
    __hip_atomic_store(&go[tid * 32], tgt, __ATOMIC_RELEASE, AGENT);
    __hip_atomic_store(&go[(tid + 256) * 32], tgt, __ATOMIC_RELEASE, AGENT);
  } else if (tid == 0) {
    while (uload(&go[blk * 32]) < tgt)
      __builtin_amdgcn_s_sleep(1);
  }
  __asm__ __volatile__("" ::: "memory");
  __syncthreads();
}

__launch_bounds__(256, 2)
__global__ void step_loop(const bf16* __restrict__ memb, const float* __restrict__ W0,
                          const float* __restrict__ bias0, const float* __restrict__ Wg,
                          const float* __restrict__ biasg2, const float* __restrict__ tgtT,
                          float* __restrict__ q2, float* __restrict__ uaccT,
                          float* __restrict__ Lacc, float* __restrict__ hTA,
                          float* __restrict__ hTB, float* __restrict__ gpart,
                          unsigned* flags, unsigned* go, unsigned* gcnt,
                          float* __restrict__ out) {
  __shared__ SMemU sm;
  const int blk = blockIdx.x, tid = threadIdx.x;
  const int b = blk >> 3, jj = blk & 7, s0 = jj * 64;   // P1 role
  const int ks = blk >> 6, nc = blk & 63;               // P2 role
  float cval = 0.f;
  int slot = 0;

  for (int t = 0; t <= 64; t++) {
    const float* hTR = (t & 1) ? hTB : hTA;
    float* hTW = (t & 1) ? hTA : hTB;

    // ============ P0: Y = h@W0 + bias0 (q2 cols + classifier cols) =========
    if (blk < 160) {
      const int bb0 = tid & 63, q = tid >> 6;   // q = k-quarter
      const int n0 = blk * 4;
      const int kq = q * 128;
      float acc[4] = {};
#pragma unroll 16
      for (int k = 0; k < 128; k++) {
        float xv = aload(&hTR[(size_t)(kq + k) * 64 + bb0]);
        acc[0] += xv * W0[(size_t)(n0 + 0) * 512 + kq + k];
        acc[1] += xv * W0[(size_t)(n0 + 1) * 512 + kq + k];
        acc[2] += xv * W0[(size_t)(n0 + 2) * 512 + kq + k];
        acc[3] += xv * W0[(size_t)(n0 + 3) * 512 + kq + k];
      }
#pragma unroll
      for (int c = 0; c < 4; c++) sm.a.sp[q * 256 + c * 64 + bb0] = acc[c];
      __syncthreads();
      {
        const int c = tid >> 6, b2 = tid & 63;
        float v = sm.a.sp[c * 64 + b2] + sm.a.sp[256 + c * 64 + b2] +
                  sm.a.sp[512 + c * 64 + b2] + sm.a.sp[768 + c * 64 + b2] + bias0[n0 + c];
        const int n = n0 + c;
        if (n < 512) astore(&q2[(size_t)b2 * 512 + n], v);
        else if (t > 0) out[((size_t)b2 * 64 + (t - 1)) * 128 + (n - 512)] = v;
      }
    } else if (blk < 288) {
      astore(&uaccT[(size_t)(blk - 160) * 256 + tid], 0.f);   // zero u-accum
    } else if (blk == 288) {
      if (tid < 64) astore(&Lacc[tid * 16], 0.f);             // zero exp-sums
    }
    if (t == 64) return;
    gbar(flags, go, slot++);

    // ============ P1: scores + exp + u-partials (8 blocks/b) ===============
    sm.a.q2L[2 * tid]     = aload(&q2[(size_t)b * 512 + 2 * tid]);
    sm.a.q2L[2 * tid + 1] = aload(&q2[(size_t)b * 512 + 2 * tid + 1]);
    __syncthreads();
    {
      // scores: s = tid>>2 (0..63), e-quarter = (tid&3)*128
      const int s = tid >> 2, eq = tid & 3;
      const uint4* mp = (const uint4*)&memb[((size_t)b << 18) + (size_t)(s0 + s) * 512 + eq * 128];
      const float4* qp = (const float4*)&sm.a.q2L[eq * 128];
      float acc = 0.f;
#pragma unroll 8
      for (int j = 0; j < 16; j++) {
        uint4 m = mp[j];
        float4 qa = qp[2 * j], qb = qp[2 * j + 1];
        float2 p0 = bf2f2(m.x), p1 = bf2f2(m.y), p2 = bf2f2(m.z), p3 = bf2f2(m.w);
        acc += p0.x * qa.x + p0.y * qa.y + p1.x * qa.z + p1.y * qa.w
             + p2.x * qb.x + p2.y * qb.y + p3.x * qb.z + p3.y * qb.w;
      }
      sm.a.sp[tid] = acc;
    }
    __syncthreads();
    if (tid < 64) {
      float sc = sm.a.sp[4 * tid] + sm.a.sp[4 * tid + 1] + sm.a.sp[4 * tid + 2] + sm.a.sp[4 * tid + 3];
      float es = __expf(sc);            // no max-sub: |score| << 1 by construction
      sm.a.p[tid] = es;
      float ls = es;
#pragma unroll
      for (int off = 32; off; off >>= 1) ls += __shfl_xor(ls, off);
      if (tid == 0) atomicAdd(&Lacc[b * 16], ls);
    }
    __syncthreads();
    {
      // u-partials: wave w covers 16 s's, lane l covers e = 8l..8l+7
      const int w = tid >> 6, l = tid & 63;
      float c8[8] = {};
      const uint4* vp = (const uint4*)&memb[((size_t)b << 18) + (size_t)(s0 + w * 16) * 512 + 8 * l];
#pragma unroll 8
      for (int i = 0; i < 16; i++) {
        float ps = sm.a.p[w * 16 + i];
        uint4 m = vp[(size_t)i * 64];
        float2 p0 = bf2f2(m.x), p1 = bf2f2(m.y), p2 = bf2f2(m.z), p3 = bf2f2(m.w);
        c8[0] += ps * p0.x; c8[1] += ps * p0.y; c8[2] += ps * p1.x; c8[3] += ps * p1.y;
        c8[4] += ps * p2.x; c8[5] += ps * p2.y; c8[6] += ps * p3.x; c8[7] += ps * p3.y;
      }
      *(float4*)&sm.a.buf[w * 520 + 8 * l]     = make_float4(c8[0], c8[1], c8[2], c8[3]);
      *(float4*)&sm.a.buf[w * 520 + 8 * l + 4] = make_float4(c8[4], c8[5], c8[6], c8[7]);
    }
    __syncthreads();
    {
      const int e = 2 * tid;
      float ux = sm.a.buf[e] + sm.a.buf[520 + e] + sm.a.buf[1040 + e] + sm.a.buf[1560 + e];
      float uy = sm.a.buf[e + 1] + sm.a.buf[520 + e + 1] + sm.a.buf[1040 + e + 1] + sm.a.buf[1560 + e + 1];
      atomicAdd(&uaccT[(size_t)e * 64 + b], ux);
      atomicAdd(&uaccT[(size_t)(e + 1) * 64 + b], uy);
    }
    gbar(flags, go, slot++);

    // ====== P2: gates GEMM (8 ks x 64 nc, 144-k tiles) + combine + cell ====
    if (tid < 64) sm.b.rL[tid] = 1.0f / aload(&Lacc[tid * 16]);
    __syncthreads();
    {
      const int k0 = ks * 144;
      for (int q = tid; q < 2304; q += 256) {
        const int row = q >> 4, c4 = (q & 15) * 4;
        const int k = k0 + row;
        if (k < 512) {
#pragma unroll
          for (int i = 0; i < 4; i++)
            sm.b.As[row][c4 + i] = aload(&uaccT[(size_t)k * 64 + c4 + i]) * sm.b.rL[c4 + i];
        } else if (k < 1024) {
#pragma unroll
          for (int i = 0; i < 4; i++)
            sm.b.As[row][c4 + i] = aload(&hTR[(size_t)(k - 512) * 64 + c4 + i]);
        } else {
          float4 xv = *(const float4*)&tgtT[((size_t)t * 128 + (k - 1024)) * 64 + c4];
          *(float4*)&sm.b.As[row][c4] = xv;
        }
      }
      for (int q = tid; q < 1152; q += 256) {
        const int row = q >> 3, c4 = (q & 7) * 4;
        *(float4*)&sm.b.Bs[row][c4] = *(const float4*)&Wg[(size_t)(k0 + row) * 2048 + nc * 32 + c4];
      }
      __syncthreads();
      const int tx = tid & 7, ty = tid >> 3;
      float acc[2][4] = {};
#pragma unroll 4
      for (int kk = 0; kk < 144; kk++) {
        float2 av = *(const float2*)&sm.b.As[kk][ty * 2];
        float4 bv = *(const float4*)&sm.b.Bs[kk][tx * 4];
        acc[0][0] += av.x * bv.x; acc[0][1] += av.x * bv.y;
        acc[0][2] += av.x * bv.z; acc[0][3] += av.x * bv.w;
        acc[1][0] += av.y * bv.x; acc[1][1] += av.y * bv.y;
        acc[1][2] += av.y * bv.z; acc[1][3] += av.y * bv.w;
      }
#pragma unroll
      for (int i = 0; i < 2; i++) {
        const size_t gp = ((size_t)ks * 64 + ty * 2 + i) * 2048 + nc * 32 + tx * 4;
        astore(&gpart[gp + 0], acc[i][0]);
        astore(&gpart[gp + 1], acc[i][1]);
        astore(&gpart[gp + 2], acc[i][2]);
        astore(&gpart[gp + 3], acc[i][3]);
      }
    }
    __syncthreads();
    if (tid == 0) {
      __hip_atomic_fetch_add(&gcnt[nc * 32], 1u, __ATOMIC_RELEASE, AGENT);
      while (uload(&gcnt[nc * 32]) < 8u * (t + 1))
        __builtin_amdgcn_s_sleep(1);
    }
    __asm__ __volatile__("" ::: "memory");
    __syncthreads();
    {
      const int bb = ks * 8 + (tid >> 5);
      const int col = tid & 31;
      const int d = nc * 8 + ((tid >> 2) & 7);
      float val = biasg2[nc * 32 + col];
#pragma unroll
      for (int k2 = 0; k2 < 8; k2++)
        val += aload(&gpart[((size_t)k2 * 64 + bb) * 2048 + nc * 32 + col]);
      const int qbase = (tid & 63) & ~3;
      float gi = __shfl(val, qbase + 0);
      float gf = __shfl(val, qbase + 1);
      float gg = __shfl(val, qbase + 2);
      float go_ = __shfl(val, qbase + 3);
      float cn = sigm(gf) * cval + sigm(gi) * tanhf(gg);
      cval = cn;
      float hn = sigm(go_) * tanhf(cn);
      if ((tid & 3) == 0) astore(&hTW[(size_t)d * 64 + bb], hn);
    }
    gbar(flags, go, slot++);
  }
}

// ---------------------------------------------------------------------------
extern "C" void kernel_launch(void* const* d_in, const int* in_sizes, int n_in,
                              void* d_out, int out_size, void* d_ws, size_t ws_size,
                              hipStream_t stream) {
  const float* memory = (const float*)d_in[0];
  const float* tgt    = (const float*)d_in[1];
  const float* Wq     = (const float*)d_in[2];
  const float* bq     = (const float*)d_in[3];
  const float* Wk     = (const float*)d_in[4];
  const float* bk     = (const float*)d_in[5];   (void)bk;
  const float* Wv     = (const float*)d_in[6];
  const float* bv     = (const float*)d_in[7];
  const float* Wo     = (const float*)d_in[8];
  const float* bo     = (const float*)d_in[9];
  const float* W_ih   = (const float*)d_in[10];
  const float* b_ih   = (const float*)d_in[11];
  const float* W_hh   = (const float*)d_in[12];
  const float* b_hh   = (const float*)d_in[13];
  const float* Wcls   = (const float*)d_in[14];
  const float* bcls   = (const float*)d_in[15];
  float* out = (float*)d_out;

  float* ws = (float*)d_ws;
  size_t off = 0;
  auto alloc = [&](size_t n) { size_t r = off; off += (n + 31) & ~(size_t)31; return r; };
  const size_t memb_off  = alloc(8388608);    // bf16 x 16.7M [b][s][e]
  const size_t Wg_off    = alloc(2359296);    // fp32 [k][j'] 1152x2048
  const size_t W0_off    = alloc(327680);     // fp32 [n][k]  640x512
  const size_t bias0_off = alloc(640);
  const size_t biasg_off = alloc(2048);
  const size_t biasg2_off= alloc(2048);
  const size_t bvo_off   = alloc(512);
  const size_t c0_off    = alloc(512);
  const size_t tgtT_off  = alloc(524288);     // [t][v][b]
  const size_t q2_off    = alloc(32768);      // [b][e]
  const size_t uaccT_off = alloc(32768);      // [e][b]
  const size_t Lacc_off  = alloc(1024);       // 64 x 16 (64B stride)
  const size_t hTA_off   = alloc(32768);      // zeroed
  const size_t sync_off  = alloc(34816);      // flags 16384u + go 16384u + gcnt 2048u (zeroed)
  const size_t hTB_off   = alloc(32768);
  const size_t gpart_off = alloc(1048576);    // 8x64x2048; doubles as U2 in precompute
  const size_t WqT_off   = alloc(262144);
  const size_t A_off     = alloc(262144);
  const size_t U1_off    = alloc(262144);

  bf16* memb = (bf16*)(ws + memb_off);
  unsigned* sync  = (unsigned*)(ws + sync_off);
  unsigned* flags = sync;
  unsigned* gosig = sync + 16384;
  unsigned* gcnt  = sync + 32768;
  float* U2 = ws + gpart_off;   // precompute alias (same size region)

  // zero hTA + sync area (contiguous region)
  hipMemsetAsync(ws + hTA_off, 0, (32768 + 34816) * sizeof(float), stream);

  // ---- precompute ----
  cast_mem<<<8192, 256, 0, stream>>>(memory, memb);
  transpose512<<<1024, 256, 0, stream>>>(Wq, ws + WqT_off);
  // A = Wq^T @ Wk
  gemm64<<<dim3(8, 8), 256, 0, stream>>>(ws + WqT_off, Wk, ws + A_off,
                                         512, 512, 512, 512, 512, 512);
  colvec_kernel<<<2, 256, 0, stream>>>(bq, Wk, ws + c0_off);    // c0 = bq@Wk
  assembleW0<<<1280, 256, 0, stream>>>(ws + A_off, Wcls, ws + c0_off, bcls,
                                       ws + W0_off, ws + bias0_off);
  // U1 = Wo@Wv ; U2 = W_ih[:, :512] @ U1  (so U2[j][e] = (Wv^T Wo^T W1^T)[e][j])
  gemm64<<<dim3(8, 8), 256, 0, stream>>>(Wo, Wv, ws + U1_off,
                                         512, 512, 512, 512, 512, 512);
  gemm64<<<dim3(8, 32), 256, 0, stream>>>(W_ih, ws + U1_off, U2,
                                          2048, 512, 512, 640, 512, 512);
  assembleWg<<<9216, 256, 0, stream>>>(U2, W_hh, W_ih, ws + Wg_off);
  bvo_kernel<<<2, 256, 0, stream>>>(bv, Wo, bo, ws + bvo_off);
  biasg_kernel<<<8, 256, 0, stream>>>(W_ih, b_ih, b_hh, ws + bvo_off, ws + biasg_off);
  reorderB<<<8, 256, 0, stream>>>(ws + biasg_off, ws + biasg2_off);
  transposeT<<<2048, 256, 0, stream>>>(tgt, ws + tgtT_off);

  // ---- all 64 recurrent steps, one persistent kernel ----
  step_loop<<<512, 256, 0, stream>>>(memb, ws + W0_off, ws + bias0_off,
                                     ws + Wg_off, ws + biasg2_off, ws + tgtT_off,
                                     ws + q2_off, ws + uaccT_off, ws + Lacc_off,
                                     ws + hTA_off, ws + hTB_off, ws + gpart_off,
                                     flags, gosig, gcnt, out);
}